// Round 6
// baseline (274.680 us; speedup 1.0000x reference)
//
#include <hip/hip_runtime.h>
#include <hip/hip_bf16.h>

typedef __bf16 bf16_t;
typedef __bf16 bf16x8 __attribute__((ext_vector_type(8)));
typedef __bf16 bf16x4 __attribute__((ext_vector_type(4)));
typedef float f32x4 __attribute__((ext_vector_type(4)));

#define AS1(p) ((const __attribute__((address_space(1))) void*)(p))
#define AS3(p) ((__attribute__((address_space(3))) void*)(p))

// scale = HEAD_DIM^-0.5 * log2(e), folded into Q at QKV-GEMM epilogue
#define QSCALE 0.1803368801111204f

// ---------------- cast X fp32 -> bf16 ----------------
__global__ void cast_x_kernel(const float* __restrict__ X, bf16_t* __restrict__ Xb) {
  int i = (blockIdx.x * 256 + threadIdx.x) * 4;
  float4 v = *(const float4*)(X + i);
  bf16x4 o;
  o[0] = (bf16_t)v.x; o[1] = (bf16_t)v.y; o[2] = (bf16_t)v.z; o[3] = (bf16_t)v.w;
  *(bf16x4*)(Xb + i) = o;
}

// ---------------- transpose + cast W [K][N] fp32 -> Wt [N][K] bf16 ----------------
__global__ void transpose_cast_kernel(const float* __restrict__ W, bf16_t* __restrict__ Wt,
                                      int K, int N) {
  __shared__ float tile[32][33];
  int n0 = blockIdx.x * 32, k0 = blockIdx.y * 32;
  int tx = threadIdx.x, ty = threadIdx.y;
  for (int r = ty; r < 32; r += 8)
    tile[r][tx] = W[(size_t)(k0 + r) * N + n0 + tx];
  __syncthreads();
  for (int r = ty; r < 32; r += 8)
    Wt[(size_t)(n0 + r) * K + k0 + tx] = (bf16_t)tile[tx][r];
}

// ---------------- QKV GEMM: C[8192,3072] = Xb[8192,1024] @ Wt[3072,1024]^T ----------------
// Q,K written [b,h,s,d] (Q pre-scaled by QSCALE); V written TRANSPOSED [b,h,d,s].
__global__ __launch_bounds__(256) void gemm_qkv_kernel(
    const bf16_t* __restrict__ A, const bf16_t* __restrict__ Bt,
    bf16_t* __restrict__ Qb, bf16_t* __restrict__ Kb, bf16_t* __restrict__ Vt) {
  __shared__ __align__(16) bf16_t As[128 * 32];
  __shared__ __align__(16) bf16_t Bs[128 * 32];
  const int tid = threadIdx.x;
  const int lane = tid & 63, wave = tid >> 6;
  const int quad = lane >> 4, l15 = lane & 15;
  const int wr = wave >> 1, wc = wave & 1;
  const int m0 = blockIdx.x * 128, n0 = blockIdx.y * 128;
  f32x4 acc[4][4];
  const f32x4 vzero = {0.f, 0.f, 0.f, 0.f};
#pragma unroll
  for (int i = 0; i < 4; i++)
#pragma unroll
    for (int j = 0; j < 4; j++) acc[i][j] = vzero;

  for (int kb = 0; kb < 1024; kb += 32) {
    __syncthreads();
#pragma unroll
    for (int i = 0; i < 2; i++) {
      int c = i * 256 + tid;
      int row = c >> 2, kc = c & 3;
      __builtin_amdgcn_global_load_lds(AS1(A + (size_t)(m0 + row) * 1024 + kb + kc * 8),
                                       AS3(As + c * 8), 16, 0, 0);
    }
#pragma unroll
    for (int i = 0; i < 2; i++) {
      int c = i * 256 + tid;
      int row = c >> 2, kc = c & 3;
      __builtin_amdgcn_global_load_lds(AS1(Bt + (size_t)(n0 + row) * 1024 + kb + kc * 8),
                                       AS3(Bs + c * 8), 16, 0, 0);
    }
    __builtin_amdgcn_s_waitcnt(0);
    __syncthreads();
    bf16x8 af[4], bfr[4];
#pragma unroll
    for (int t = 0; t < 4; t++) {
      af[t]  = *(const bf16x8*)(As + (wr * 64 + t * 16 + l15) * 32 + quad * 8);
      bfr[t] = *(const bf16x8*)(Bs + (wc * 64 + t * 16 + l15) * 32 + quad * 8);
    }
#pragma unroll
    for (int mt = 0; mt < 4; mt++)
#pragma unroll
      for (int nt = 0; nt < 4; nt++)
        acc[mt][nt] = __builtin_amdgcn_mfma_f32_16x16x32_bf16(af[mt], bfr[nt], acc[mt][nt], 0, 0, 0);
  }
  // C layout: col=lane&15, row=quad*4+reg
#pragma unroll
  for (int nt = 0; nt < 4; nt++) {
    int gn = n0 + wc * 64 + nt * 16 + l15;
    int which = gn >> 10;   // 0=Q, 1=K, 2=V (uniform across lanes per nt)
    int rem = gn & 1023;
    int hh = rem >> 6, dd = rem & 63;
    if (which == 2) {
      // V transposed: Vt[b][h][dd][s], r-dim is consecutive s -> 8B vector store
#pragma unroll
      for (int mt = 0; mt < 4; mt++) {
        int gm0 = m0 + wr * 64 + mt * 16 + quad * 4;
        int b = gm0 >> 11, s = gm0 & 2047;
        bf16x4 o;
#pragma unroll
        for (int r = 0; r < 4; r++) o[r] = (bf16_t)acc[mt][nt][r];
        *(bf16x4*)(Vt + ((size_t)((b << 4) + hh) * 64 + dd) * 2048 + s) = o;
      }
    } else {
      bf16_t* dst = (which == 0) ? Qb : Kb;
      float scl = (which == 0) ? QSCALE : 1.0f;
#pragma unroll
      for (int mt = 0; mt < 4; mt++) {
#pragma unroll
        for (int r = 0; r < 4; r++) {
          int gm = m0 + wr * 64 + mt * 16 + quad * 4 + r;
          int b = gm >> 11, s = gm & 2047;
          dst[((size_t)((b << 4) + hh) * 2048 + s) * 64 + dd] = (bf16_t)(acc[mt][nt][r] * scl);
        }
      }
    }
  }
}

// ---------------- Flash attention, causal, no-max softmax, P-in-registers ----------------
// 512 blocks = 64 bh x 8 pairs {qb, 15-qb}, 17 KV-iters each, 2 blocks/CU.
// Key trick: compute S^T = mfma(A=K,B=Q); with K rows PERMUTED in LDS
// (key = g*32 + quad*8 + b*4 + r at LDS row g*32+b*16+quad*4+r), the two 16-key
// S^T tiles of a 32-key group pack in registers into exactly the A-operand
// layout (k=quad*8+j) of the PV mfma_16x16x32 -> P never touches LDS.
// Row-sums: per-lane f32 adds (each lane's P all belongs to query l15),
// cross-quad reduction deferred to epilogue (2 shuffles).
__global__ __launch_bounds__(256, 3) void attn_kernel(
    const bf16_t* __restrict__ Qg_, const bf16_t* __restrict__ Kg_,
    const bf16_t* __restrict__ Vtg_, bf16_t* __restrict__ ctx) {
  __shared__ __align__(16) bf16_t Ks[128 * 72];   // [key_perm][d] pad 72 (18 KB)
  __shared__ __align__(16) bf16_t Vst[64 * 136];  // [d][key] pad 136     (17 KB)
  const int tid = threadIdx.x;
  const int lane = tid & 63, w = tid >> 6;
  const int quad = lane >> 4, l15 = lane & 15;

  const int bh = blockIdx.x >> 3;   // 0..63
  const int pp = blockIdx.x & 7;    // 0..7 -> pair {pp, 15-pp}
  const int b = bh >> 4, h = bh & 15;
  const size_t base = (size_t)bh * 2048 * 64;
  const bf16_t* Kg = Kg_ + base;
  const bf16_t* Vtg = Vtg_ + base;  // [d][s]

  // prefetch K/V tile j=0 into registers
  bf16x8 kr[4], vr[4];
#pragma unroll
  for (int i = 0; i < 4; i++) {
    int c = i * 256 + tid;
    int r = c >> 3, dc = c & 7;
    kr[i] = *(const bf16x8*)(Kg + (size_t)r * 64 + dc * 8);
  }
#pragma unroll
  for (int i = 0; i < 4; i++) {
    int c = i * 256 + tid;
    int r = c >> 4, cc = c & 15;
    vr[i] = *(const bf16x8*)(Vtg + (size_t)r * 2048 + cc * 8);
  }

  const f32x4 vzero = {0.f, 0.f, 0.f, 0.f};

  for (int ti = 0; ti < 2; ti++) {
    const int qb = (ti == 0) ? pp : 15 - pp;
    const int L = qb + 1;

    // Q fragments: wave owns rows qb*128 + w*32 + mt*16 + l15
    bf16x8 aq[2][2];
#pragma unroll
    for (int mt = 0; mt < 2; mt++)
#pragma unroll
      for (int ks = 0; ks < 2; ks++)
        aq[mt][ks] = *(const bf16x8*)(Qg_ + base +
                                      (size_t)(qb * 128 + w * 32 + mt * 16 + l15) * 64 +
                                      ks * 32 + quad * 8);

    f32x4 Oacc[2][4];
    float rsum[2];
#pragma unroll
    for (int mt = 0; mt < 2; mt++) {
#pragma unroll
      for (int dt = 0; dt < 4; dt++) Oacc[mt][dt] = vzero;
      rsum[mt] = 0.f;
    }

    for (int j = 0; j < L; j++) {
      __syncthreads();  // prior iter's Ks/Vst reads done
      // stage K with permuted rows: LDS row kp <-> actual key k
      // k bits [4:3]=quad,[2]=b,[1:0]=r  ->  kp = g<<5 | b<<4 | quad<<2 | r
#pragma unroll
      for (int i = 0; i < 4; i++) {
        int c = i * 256 + tid;
        int k = c >> 3, dc = c & 7;
        int kp = (k & 0x60) | ((k & 4) << 2) | ((k & 0x18) >> 1) | (k & 3);
        *(bf16x8*)(Ks + kp * 72 + dc * 8) = kr[i];
      }
#pragma unroll
      for (int i = 0; i < 4; i++) {
        int c = i * 256 + tid;
        int r = c >> 4, cc = c & 15;
        *(bf16x8*)(Vst + r * 136 + cc * 8) = vr[i];
      }
      __syncthreads();

      // prefetch next K/V tile (same bh; next Q-tile restarts at j=0)
      const bool havenext = (j + 1 < L) || (ti == 0);
      if (havenext) {
        const int jn = (j + 1 < L) ? j + 1 : 0;
#pragma unroll
        for (int i = 0; i < 4; i++) {
          int c = i * 256 + tid;
          int r = c >> 3, dc = c & 7;
          kr[i] = *(const bf16x8*)(Kg + ((size_t)jn * 128 + r) * 64 + dc * 8);
        }
#pragma unroll
        for (int i = 0; i < 4; i++) {
          int c = i * 256 + tid;
          int r = c >> 4, cc = c & 15;
          vr[i] = *(const bf16x8*)(Vtg + (size_t)r * 2048 + jn * 128 + cc * 8);
        }
      }

      const bool diag = (j == L - 1);

      // process 32-key groups: S^T via swapped-operand MFMA, P stays in registers
#pragma unroll
      for (int g = 0; g < 4; g++) {
        f32x4 sch[2][2];
#pragma unroll
        for (int bs = 0; bs < 2; bs++) {
          const int nt = 2 * g + bs;
          bf16x8 bk0 = *(const bf16x8*)(Ks + (nt * 16 + l15) * 72 + quad * 8);
          bf16x8 bk1 = *(const bf16x8*)(Ks + (nt * 16 + l15) * 72 + 32 + quad * 8);
#pragma unroll
          for (int mt = 0; mt < 2; mt++) {
            f32x4 s0 = __builtin_amdgcn_mfma_f32_16x16x32_bf16(bk0, aq[mt][0], vzero, 0, 0, 0);
            sch[bs][mt] = __builtin_amdgcn_mfma_f32_16x16x32_bf16(bk1, aq[mt][1], s0, 0, 0, 0);
          }
        }
        // mask (diag tile only) + exp2 + pack into PV A-fragments + row-sum
        bf16x8 pfrag[2];
#pragma unroll
        for (int mt = 0; mt < 2; mt++) {
          const int qg_ = qb * 128 + w * 32 + mt * 16 + l15;
#pragma unroll
          for (int bs = 0; bs < 2; bs++) {
            const int kb_ = j * 128 + g * 32 + quad * 8 + bs * 4;
#pragma unroll
            for (int r = 0; r < 4; r++) {
              float x = sch[bs][mt][r];
              if (diag && (kb_ + r > qg_)) x = -INFINITY;
              float p = __builtin_exp2f(x);
              rsum[mt] += p;
              pfrag[mt][bs * 4 + r] = (bf16_t)p;
            }
          }
        }
        // O += P @ V for this 32-key group (V in natural key order)
#pragma unroll
        for (int dt = 0; dt < 4; dt++) {
          bf16x8 bv = *(const bf16x8*)(Vst + (dt * 16 + l15) * 136 + g * 32 + quad * 8);
#pragma unroll
          for (int mt = 0; mt < 2; mt++)
            Oacc[mt][dt] = __builtin_amdgcn_mfma_f32_16x16x32_bf16(pfrag[mt], bv, Oacc[mt][dt], 0, 0, 0);
        }
      }
    }

    // epilogue: reduce rsum across quads, redistribute to D-layout rows, write ctx
#pragma unroll
    for (int mt = 0; mt < 2; mt++) {
      float s = rsum[mt];
      s += __shfl_xor(s, 16);
      s += __shfl_xor(s, 32);          // all lanes now hold L[q = l15]
      float rl[4];
#pragma unroll
      for (int r = 0; r < 4; r++)
        rl[r] = __builtin_amdgcn_rcpf(__shfl(s, quad * 4 + r));  // L[q = quad*4+r]
#pragma unroll
      for (int dt = 0; dt < 4; dt++)
#pragma unroll
        for (int r = 0; r < 4; r++) {
          int qg = qb * 128 + w * 32 + mt * 16 + quad * 4 + r;
          ctx[((size_t)b * 2048 + qg) * 1024 + h * 64 + dt * 16 + l15] =
              (bf16_t)(Oacc[mt][dt][r] * rl[r]);
        }
    }
  }
}

// ---------------- out proj: out[8192,1024] = ctx @ Wout^T + b ----------------
__global__ __launch_bounds__(256) void gemm_out_kernel(
    const bf16_t* __restrict__ A, const bf16_t* __restrict__ Bt,
    const float* __restrict__ bias, float* __restrict__ out) {
  __shared__ __align__(16) bf16_t As[128 * 32];
  __shared__ __align__(16) bf16_t Bs[128 * 32];
  const int tid = threadIdx.x;
  const int lane = tid & 63, wave = tid >> 6;
  const int quad = lane >> 4, l15 = lane & 15;
  const int wr = wave >> 1, wc = wave & 1;
  const int m0 = blockIdx.x * 128, n0 = blockIdx.y * 128;
  f32x4 acc[4][4];
  const f32x4 vzero = {0.f, 0.f, 0.f, 0.f};
#pragma unroll
  for (int i = 0; i < 4; i++)
#pragma unroll
    for (int j = 0; j < 4; j++) acc[i][j] = vzero;

  for (int kb = 0; kb < 1024; kb += 32) {
    __syncthreads();
#pragma unroll
    for (int i = 0; i < 2; i++) {
      int c = i * 256 + tid;
      int row = c >> 2, kc = c & 3;
      __builtin_amdgcn_global_load_lds(AS1(A + (size_t)(m0 + row) * 1024 + kb + kc * 8),
                                       AS3(As + c * 8), 16, 0, 0);
    }
#pragma unroll
    for (int i = 0; i < 2; i++) {
      int c = i * 256 + tid;
      int row = c >> 2, kc = c & 3;
      __builtin_amdgcn_global_load_lds(AS1(Bt + (size_t)(n0 + row) * 1024 + kb + kc * 8),
                                       AS3(Bs + c * 8), 16, 0, 0);
    }
    __builtin_amdgcn_s_waitcnt(0);
    __syncthreads();
    bf16x8 af[4], bfr[4];
#pragma unroll
    for (int t = 0; t < 4; t++) {
      af[t]  = *(const bf16x8*)(As + (wr * 64 + t * 16 + l15) * 32 + quad * 8);
      bfr[t] = *(const bf16x8*)(Bs + (wc * 64 + t * 16 + l15) * 32 + quad * 8);
    }
#pragma unroll
    for (int mt = 0; mt < 4; mt++)
#pragma unroll
      for (int nt = 0; nt < 4; nt++)
        acc[mt][nt] = __builtin_amdgcn_mfma_f32_16x16x32_bf16(af[mt], bfr[nt], acc[mt][nt], 0, 0, 0);
  }
#pragma unroll
  for (int nt = 0; nt < 4; nt++) {
    int gn = n0 + wc * 64 + nt * 16 + l15;
    float bv = bias[gn];
#pragma unroll
    for (int mt = 0; mt < 4; mt++) {
#pragma unroll
      for (int r = 0; r < 4; r++) {
        int gm = m0 + wr * 64 + mt * 16 + quad * 4 + r;
        out[(size_t)gm * 1024 + gn] = acc[mt][nt][r] + bv;
      }
    }
  }
}

extern "C" void kernel_launch(void* const* d_in, const int* in_sizes, int n_in,
                              void* d_out, int out_size, void* d_ws, size_t ws_size,
                              hipStream_t stream) {
  (void)in_sizes; (void)n_in; (void)out_size; (void)ws_size;
  const float* X     = (const float*)d_in[0];  // [4,2048,1024]
  const float* W_qkv = (const float*)d_in[1];  // [1024,3072]
  const float* W_out = (const float*)d_in[2];  // [1024,1024]
  const float* b_out = (const float*)d_in[3];  // [1024]
  float* out = (float*)d_out;                  // [4,2048,1024] fp32

  char* ws = (char*)d_ws;
  bf16_t* Xb    = (bf16_t*)(ws);               // 16 MB
  bf16_t* Wqkvt = (bf16_t*)(ws + 16777216);    // 6 MB   [3072][1024]
  bf16_t* Woutt = (bf16_t*)(ws + 23068672);    // 2 MB   [1024][1024]
  bf16_t* Qb    = (bf16_t*)(ws + 25165824);    // 16 MB  [b,h,s,d]
  bf16_t* Kb    = (bf16_t*)(ws + 41943040);    // 16 MB  [b,h,s,d]
  bf16_t* Vt    = (bf16_t*)(ws + 58720256);    // 16 MB  [b,h,d,s] (written directly by GEMM)
  bf16_t* ctx   = (bf16_t*)(ws + 75497472);    // 16 MB  [b,s,1024]

  cast_x_kernel<<<8192, 256, 0, stream>>>(X, Xb);
  transpose_cast_kernel<<<dim3(96, 32), dim3(32, 8), 0, stream>>>(W_qkv, Wqkvt, 1024, 3072);
  transpose_cast_kernel<<<dim3(32, 32), dim3(32, 8), 0, stream>>>(W_out, Woutt, 1024, 1024);
  gemm_qkv_kernel<<<dim3(64, 24), 256, 0, stream>>>(Xb, Wqkvt, Qb, Kb, Vt);
  attn_kernel<<<dim3(512), 256, 0, stream>>>(Qb, Kb, Vt, ctx);
  gemm_out_kernel<<<dim3(64, 8), 256, 0, stream>>>(ctx, Woutt, b_out, out);
}